// Round 1
// baseline (331.990 us; speedup 1.0000x reference)
//
#include <hip/hip_runtime.h>

// Series decomposition: T = moving_avg_C(x, k=25, replicate pad), xd = x - T,
// S = per-phase (c % 24) mean over the 14 groups of xd, R = xd - S.
// x: [B=32, C=336, H*W=1024] fp32. Outputs T,S,R concatenated in d_out.
//
// Layout: hw is the contiguous axis -> lanes map to hw (coalesced), loop over c.
// Block = 448 threads = 7 waves; wave s owns channel segment [48*s, 48*s+48)
// (48 = 2*24 keeps the phase index compile-time constant under unroll) for a
// 64-wide hw tile. Phase partial sums cross waves via padded LDS.
// Sweep 2 recomputes the trend (L1/L2-hot re-reads) instead of reading back T.

#define C_TOT 336
#define HWSZ 1024
#define PERIOD 24
#define PAD 12          // (25-1)/2
#define SEGS 7
#define SEG_C 48        // channels per segment (7 * 48 = 336)
#define HW_TILE 64
#define NTHREADS (SEGS * HW_TILE)  // 448 = 7 waves

__global__ __launch_bounds__(NTHREADS) void decomp_kernel(
    const float* __restrict__ x,
    float* __restrict__ outT,
    float* __restrict__ outS,
    float* __restrict__ outR)
{
    __shared__ float lds[SEGS][HW_TILE][PERIOD + 1];  // +1 pad: conflict-free

    const int t    = threadIdx.x;
    const int hw_l = t & (HW_TILE - 1);  // lane within wave -> hw (coalesced)
    const int seg  = t >> 6;             // wave id -> channel segment
    const int b    = blockIdx.y;
    const int hw   = blockIdx.x * HW_TILE + hw_l;

    const size_t base = (size_t)b * C_TOT * HWSZ + hw;
    const float* __restrict__ xb = x    + base;
    float* __restrict__ Tb       = outT + base;
    float* __restrict__ Sb       = outS + base;
    float* __restrict__ Rb       = outR + base;

    const int   c0    = seg * SEG_C;
    const float inv25 = 1.0f / 25.0f;
    const float inv14 = 1.0f / 14.0f;

    // ---------------- Sweep 1: trend (write T) + per-phase partial sums ----
    float acc[PERIOD];
    #pragma unroll
    for (int p = 0; p < PERIOD; ++p) acc[p] = 0.0f;

    float winsum = 0.0f;
    #pragma unroll
    for (int d = -PAD; d <= PAD; ++d) {
        int cc = c0 + d;
        cc = cc < 0 ? 0 : cc;            // c0+12 <= 300, upper clamp not needed
        winsum += xb[cc * HWSZ];
    }

    #pragma unroll
    for (int j = 0; j < SEG_C / PERIOD; ++j) {
        #pragma unroll
        for (int p = 0; p < PERIOD; ++p) {
            const int c = c0 + j * PERIOD + p;
            const float tval = winsum * inv25;
            Tb[c * HWSZ] = tval;
            const float xv = xb[c * HWSZ];
            acc[p] += xv - tval;         // phase = c % 24 == p (c0 % 24 == 0)
            int chi = c + 1 + PAD; chi = chi > C_TOT - 1 ? C_TOT - 1 : chi;
            int clo = c - PAD;     clo = clo < 0 ? 0 : clo;
            winsum += xb[chi * HWSZ] - xb[clo * HWSZ];
        }
    }

    // ---------------- Cross-segment phase-sum exchange via LDS -------------
    #pragma unroll
    for (int p = 0; p < PERIOD; ++p) lds[seg][hw_l][p] = acc[p];
    __syncthreads();

    float sv[PERIOD];
    #pragma unroll
    for (int p = 0; p < PERIOD; ++p) {
        float s = 0.0f;
        #pragma unroll
        for (int sgi = 0; sgi < SEGS; ++sgi) s += lds[sgi][hw_l][p];
        sv[p] = s * inv14;               // seasonal value for phase p
    }

    // ---------------- Sweep 2: recompute trend, write S and R --------------
    winsum = 0.0f;
    #pragma unroll
    for (int d = -PAD; d <= PAD; ++d) {
        int cc = c0 + d;
        cc = cc < 0 ? 0 : cc;
        winsum += xb[cc * HWSZ];
    }

    #pragma unroll
    for (int j = 0; j < SEG_C / PERIOD; ++j) {
        #pragma unroll
        for (int p = 0; p < PERIOD; ++p) {
            const int c = c0 + j * PERIOD + p;
            const float tval = winsum * inv25;
            const float xv = xb[c * HWSZ];
            const float xd = xv - tval;
            Sb[c * HWSZ] = sv[p];
            Rb[c * HWSZ] = xd - sv[p];
            int chi = c + 1 + PAD; chi = chi > C_TOT - 1 ? C_TOT - 1 : chi;
            int clo = c - PAD;     clo = clo < 0 ? 0 : clo;
            winsum += xb[chi * HWSZ] - xb[clo * HWSZ];
        }
    }
}

extern "C" void kernel_launch(void* const* d_in, const int* in_sizes, int n_in,
                              void* d_out, int out_size, void* d_ws, size_t ws_size,
                              hipStream_t stream) {
    const float* x = (const float*)d_in[0];
    // d_in[1] = kernel_size (25), d_in[2] = pe (24): fixed by setup, compiled in.
    float* out = (float*)d_out;
    const size_t N = (size_t)32 * C_TOT * HWSZ;  // 11,010,048 per output tensor

    dim3 grid(HWSZ / HW_TILE, 32);  // (16 hw-tiles, 32 batches) = 512 blocks
    decomp_kernel<<<grid, NTHREADS, 0, stream>>>(x, out, out + N, out + 2 * N);
}

// Round 2
// 174.679 us; speedup vs baseline: 1.9006x; 1.9006x over previous
//
#include <hip/hip_runtime.h>

// Series decomposition: T = moving_avg_C(x, k=25, replicate pad), xd = x - T,
// S = per-phase (c % 24) mean over G=14 groups of xd, R = xd - S.
// x: [B=32, C=336, HW=1024] fp32; outputs T,S,R concatenated in d_out.
//
// R2 design: one block = one (b, 32-wide hw tile), staging the FULL 336-channel
// column into LDS (43 KB) so every element is fetched from HBM exactly once.
// Thread (seg, col): seg in [0,14) owns channels [24*seg, 24*seg+24) -> each
// phase appears exactly once per thread (no dynamic phase indexing).
// After the window pass, xd overwrites sx in place (sync-guarded) and a
// cross-segment phase reduction produces sv[24][32].
// All T/S/R stores are non-temporal to avoid L2 write-allocate (R1 showed
// WRITE_SIZE 2.5x ideal + FETCH inflated by ~132 MB = write-allocate signature).

#define C_TOT 336
#define HWSZ 1024
#define PERIOD 24
#define GROUPS 14         // C_TOT / PERIOD
#define PAD 12            // (25-1)/2
#define W 32              // hw tile width (floats) -> LDS row = 128 B
#define NTHREADS 448      // 14 segments * 32 cols = 7 waves

__global__ __launch_bounds__(NTHREADS) void decomp_kernel(
    const float* __restrict__ x,
    float* __restrict__ outT,
    float* __restrict__ outS,
    float* __restrict__ outR)
{
    __shared__ float sx[C_TOT][W];     // 43008 B ; bank = col -> 2-way max (free)
    __shared__ float sv[PERIOD][W];    // 3072 B

    const int tid = threadIdx.x;
    const int b   = blockIdx.y;
    const int hw0 = blockIdx.x * W;

    // ---- Stage x[b, :, hw0:hw0+32] -> LDS (float4, each element read once) ----
    const float4* __restrict__ xg =
        (const float4*)(x + (size_t)b * C_TOT * HWSZ + hw0);
    float4* __restrict__ sx4 = (float4*)sx;
    #pragma unroll
    for (int k = 0; k < (C_TOT * W / 4) / NTHREADS; ++k) {   // 2688/448 = 6
        const int idx = tid + k * NTHREADS;                  // 0..2687
        sx4[idx] = xg[(idx >> 3) * (HWSZ / 4) + (idx & 7)];
    }
    __syncthreads();

    // ---- Window pass: trend (write T), keep xd in registers ----
    const int col = tid & (W - 1);
    const int seg = tid >> 5;          // 0..13
    const int c0  = seg * PERIOD;
    const float inv25 = 1.0f / 25.0f;
    const float inv14 = 1.0f / (float)GROUPS;

    const size_t base = (size_t)b * C_TOT * HWSZ + hw0 + col;
    float* __restrict__ Tb = outT + base;
    float* __restrict__ Sb = outS + base;
    float* __restrict__ Rb = outR + base;

    float winsum = 0.0f;
    #pragma unroll
    for (int d = -PAD; d <= PAD; ++d) {
        int cc = c0 + d;
        cc = cc < 0 ? 0 : cc;          // c0+PAD <= 324 < 336: no upper clamp
        winsum += sx[cc][col];
    }

    float xd[PERIOD];
    #pragma unroll
    for (int p = 0; p < PERIOD; ++p) {
        const int c = c0 + p;
        const float tval = winsum * inv25;
        __builtin_nontemporal_store(tval, &Tb[(size_t)c * HWSZ]);
        xd[p] = sx[c][col] - tval;
        int chi = c + 1 + PAD; chi = chi > C_TOT - 1 ? C_TOT - 1 : chi;
        int clo = c - PAD;     clo = clo < 0 ? 0 : clo;
        winsum += sx[chi][col] - sx[clo][col];
    }
    __syncthreads();                    // all window reads of sx done

    // ---- Overwrite sx with xd, then cross-segment phase reduction ----
    #pragma unroll
    for (int p = 0; p < PERIOD; ++p) sx[c0 + p][col] = xd[p];
    __syncthreads();

    for (int idx = tid; idx < PERIOD * W; idx += NTHREADS) {  // 768 items
        const int p = idx >> 5, cc = idx & (W - 1);
        float s = 0.0f;
        #pragma unroll
        for (int g = 0; g < GROUPS; ++g) s += sx[g * PERIOD + p][cc];
        sv[p][cc] = s * inv14;
    }
    __syncthreads();

    // ---- Emit S and R ----
    #pragma unroll
    for (int p = 0; p < PERIOD; ++p) {
        const int c = c0 + p;
        const float s = sv[p][col];
        __builtin_nontemporal_store(s, &Sb[(size_t)c * HWSZ]);
        __builtin_nontemporal_store(xd[p] - s, &Rb[(size_t)c * HWSZ]);
    }
}

extern "C" void kernel_launch(void* const* d_in, const int* in_sizes, int n_in,
                              void* d_out, int out_size, void* d_ws, size_t ws_size,
                              hipStream_t stream) {
    const float* x = (const float*)d_in[0];
    // d_in[1] = kernel_size (25), d_in[2] = pe (24): fixed by setup, compiled in.
    float* out = (float*)d_out;
    const size_t N = (size_t)32 * C_TOT * HWSZ;  // 11,010,048 per output tensor

    dim3 grid(HWSZ / W, 32);  // (32 hw tiles, 32 batches) = 1024 blocks
    decomp_kernel<<<grid, NTHREADS, 0, stream>>>(x, out, out + N, out + 2 * N);
}

// Round 3
// 172.897 us; speedup vs baseline: 1.9202x; 1.0103x over previous
//
#include <hip/hip_runtime.h>

// Series decomposition: T = moving_avg_C(x, k=25, replicate pad), xd = x - T,
// S = per-phase (c % 24) mean over G=14 groups of xd, R = xd - S.
// x: [B=32, C=336, HW=1024] fp32; outputs T,S,R concatenated in d_out.
//
// R3: occupancy attack. R2 had VGPR_Count=128 (xd[24] + deep staging pipe),
// which caps occupancy at 4 waves/SIMD (16 waves/CU) -> latency-bound at
// ~3.3 TB/s effective. Here each thread owns only 12 channels (28 segments x
// 32 cols = 896 threads = 14 waves/block) and __launch_bounds__(896, 8)
// forces VGPRs <= 64 -> 8 waves/SIMD bucket -> 2 resident blocks = 28
// waves/CU (LDS 2x45 KiB = 90 KiB fits). All global access remains 128 B
// per 32 lanes; stores stay non-temporal (write-allocate fix from R2).

#define C_TOT 336
#define HWSZ 1024
#define PERIOD 24
#define GROUPS 14         // C_TOT / PERIOD
#define PAD 12            // (25-1)/2
#define W 32              // hw tile width (floats) -> 128 B rows
#define SEG_C 12          // channels per thread
#define NSEG 28           // C_TOT / SEG_C
#define NTHREADS (NSEG * W)   // 896 = 14 waves

__global__ __launch_bounds__(NTHREADS, 8) void decomp_kernel(
    const float* __restrict__ x,
    float* __restrict__ outT,
    float* __restrict__ outS,
    float* __restrict__ outR)
{
    __shared__ float sx[C_TOT][W];     // 43008 B; bank = col -> 2-way max (free)
    __shared__ float sv[PERIOD][W];    // 3072 B

    const int tid = threadIdx.x;
    const int b   = blockIdx.y;
    const int hw0 = blockIdx.x * W;

    // ---- Stage x[b, :, hw0:hw0+32] -> LDS; 2688 float4, 3 per thread ----
    const float4* __restrict__ xg =
        (const float4*)(x + (size_t)b * C_TOT * HWSZ + hw0);
    float4* __restrict__ sx4 = (float4*)sx;
    #pragma unroll
    for (int k = 0; k < 3; ++k) {
        const int idx = tid + k * NTHREADS;                  // 0..2687
        sx4[idx] = xg[(idx >> 3) * (HWSZ / 4) + (idx & 7)];
    }
    __syncthreads();

    const int col = tid & (W - 1);
    const int seg = tid >> 5;          // 0..27
    const int c0  = seg * SEG_C;       // 0..324
    const float inv25 = 1.0f / 25.0f;
    const float inv14 = 1.0f / (float)GROUPS;

    const size_t base = (size_t)b * C_TOT * HWSZ + hw0 + col;
    float* __restrict__ Tb = outT + base;
    float* __restrict__ Sb = outS + base;
    float* __restrict__ Rb = outR + base;

    // ---- Window prologue: sum of x[c0-12 .. c0+12], two independent chains ----
    float wa = 0.0f, wb = 0.0f;
    #pragma unroll
    for (int d = -PAD; d <= PAD; d += 2) {
        int cc = c0 + d;
        cc = cc < 0 ? 0 : cc; cc = cc > C_TOT - 1 ? C_TOT - 1 : cc;
        wa += sx[cc][col];
    }
    #pragma unroll
    for (int d = -PAD + 1; d <= PAD; d += 2) {
        int cc = c0 + d;
        cc = cc < 0 ? 0 : cc; cc = cc > C_TOT - 1 ? C_TOT - 1 : cc;
        wb += sx[cc][col];
    }
    float winsum = wa + wb;

    // ---- Window pass: write T (nt), keep xd in registers ----
    float xd[SEG_C];
    #pragma unroll
    for (int j = 0; j < SEG_C; ++j) {
        const int c = c0 + j;
        const float tval = winsum * inv25;
        __builtin_nontemporal_store(tval, &Tb[(size_t)c * HWSZ]);
        xd[j] = sx[c][col] - tval;
        int chi = c + 1 + PAD; chi = chi > C_TOT - 1 ? C_TOT - 1 : chi;
        int clo = c - PAD;     clo = clo < 0 ? 0 : clo;
        winsum += sx[chi][col] - sx[clo][col];
    }
    __syncthreads();                    // all window reads of sx done

    // ---- Overwrite sx with xd, then cross-group phase reduction ----
    #pragma unroll
    for (int j = 0; j < SEG_C; ++j) sx[c0 + j][col] = xd[j];
    __syncthreads();

    if (tid < PERIOD * W) {             // 768 items; waves 12-13 idle (uniform)
        const int p = tid >> 5, cc = tid & (W - 1);
        float s = 0.0f;
        #pragma unroll
        for (int g = 0; g < GROUPS; ++g) s += sx[g * PERIOD + p][cc];
        sv[p][cc] = s * inv14;
    }
    __syncthreads();

    // ---- Emit S and R (nt) ----
    const int pbase = (seg & 1) * SEG_C;   // phase of xd[j] is pbase + j
    #pragma unroll
    for (int j = 0; j < SEG_C; ++j) {
        const int c = c0 + j;
        const float s = sv[pbase + j][col];
        __builtin_nontemporal_store(s, &Sb[(size_t)c * HWSZ]);
        __builtin_nontemporal_store(xd[j] - s, &Rb[(size_t)c * HWSZ]);
    }
}

extern "C" void kernel_launch(void* const* d_in, const int* in_sizes, int n_in,
                              void* d_out, int out_size, void* d_ws, size_t ws_size,
                              hipStream_t stream) {
    const float* x = (const float*)d_in[0];
    // d_in[1] = kernel_size (25), d_in[2] = pe (24): fixed by setup, compiled in.
    float* out = (float*)d_out;
    const size_t N = (size_t)32 * C_TOT * HWSZ;  // 11,010,048 per output tensor

    dim3 grid(HWSZ / W, 32);  // (32 hw tiles, 32 batches) = 1024 blocks
    decomp_kernel<<<grid, NTHREADS, 0, stream>>>(x, out, out + N, out + 2 * N);
}